// Round 6
// baseline (511.286 us; speedup 1.0000x reference)
//
#include <hip/hip_runtime.h>
#include <hip/hip_bf16.h>

#define N_UTT 4000
#define NDIM 256
#define B_DIA 100
#define L_DIA 40
#define NNODE 12000   // 3*N_UTT
#define NLAYERS 4
#define NBLK 256      // grid size; must match launch

typedef __attribute__((ext_vector_type(8))) short short8;   // 8 bf16 (4 VGPRs)
typedef __attribute__((ext_vector_type(4))) float f32x4;    // MFMA acc

union bfpk2 { __hip_bfloat16 h[2]; unsigned int u; };
union bfpk4 { __hip_bfloat16 h[4]; uint2 u; };

// LDS reused across phases (max member ~25.3 KB -> >=2 blocks/CU capacity)
union SharedU {
  struct { float tile[64][65]; } wt;                                   // 16.6 KB
  struct { float wsum[4]; } bx;
  struct { float sim_s[3][L_DIA][41]; float cr_s[3][L_DIA];
           float dinv_s[3][L_DIA]; } gr;                               // 20.6 KB
  struct { unsigned short sup[48][264]; } ly;                          // 25.3 KB
};

// ---------------------------------------------------------------------------
// device-wide sense-reversing barrier (agent scope; all NBLK blocks resident)
__device__ __forceinline__ void gsync(unsigned int* cnt, unsigned int* gen) {
  __syncthreads();
  if (threadIdx.x == 0) {
    __threadfence();   // make this block's prior writes visible device-wide
    unsigned int g = __hip_atomic_load(gen, __ATOMIC_RELAXED, __HIP_MEMORY_SCOPE_AGENT);
    unsigned int a = __hip_atomic_fetch_add(cnt, 1u, __ATOMIC_ACQ_REL, __HIP_MEMORY_SCOPE_AGENT);
    if (a == (unsigned int)(NBLK - 1)) {
      __hip_atomic_store(cnt, 0u, __ATOMIC_RELAXED, __HIP_MEMORY_SCOPE_AGENT);
      __hip_atomic_store(gen, g + 1u, __ATOMIC_RELEASE, __HIP_MEMORY_SCOPE_AGENT);
    } else {
      unsigned int cur;
      do {
        __builtin_amdgcn_s_sleep(2);
        cur = __hip_atomic_load(gen, __ATOMIC_ACQUIRE, __HIP_MEMORY_SCOPE_AGENT);
      } while (cur == g);
    }
    __threadfence();
  }
  __syncthreads();
}

// ---------------------------------------------------------------------------
// P0 task A: build x row r; write x-part of out, xb, xnb
__device__ __forceinline__ void build_x_row(
    int r, const float* __restrict__ a, const float* __restrict__ v,
    const float* __restrict__ l, const float* __restrict__ qmask,
    const float* __restrict__ spk, float* __restrict__ out,
    __hip_bfloat16* __restrict__ xb, __hip_bfloat16* __restrict__ xnb,
    SharedU& sh) {
  int t = threadIdx.x;
  int m = r / N_UTT;
  int i = r - m * N_UTT;
  float val;
  if (m == 0) val = a[i * NDIM + t];
  else if (m == 1) val = v[i * NDIM + t];
  else {
    int b = i / L_DIA, p = i - b * L_DIA;
    float q0 = qmask[p * (B_DIA * 2) + b * 2 + 0];
    float q1 = qmask[p * (B_DIA * 2) + b * 2 + 1];
    int s = (q1 > q0) ? 1 : 0;
    val = l[i * NDIM + t] + spk[s * NDIM + t];
  }
  out[i * 1536 + m * 512 + t] = val;
  xb[r * NDIM + t] = __float2bfloat16(val);
  float ss = val * val;
  #pragma unroll
  for (int off = 32; off > 0; off >>= 1) ss += __shfl_down(ss, off);
  int wid = t >> 6, lane = t & 63;
  if (lane == 0) sh.bx.wsum[wid] = ss;
  __syncthreads();
  float inv = rsqrtf(sh.bx.wsum[0] + sh.bx.wsum[1] + sh.bx.wsum[2] + sh.bx.wsum[3]);
  xnb[r * NDIM + t] = __float2bfloat16(val * inv);
}

// P0 task B: weight transpose tile idx (0..79): Wt[g][n][k] = W_g[k][n]
__device__ __forceinline__ void wt_tile(
    int idx, const float* __restrict__ W0, const float* __restrict__ Wc,
    __hip_bfloat16* __restrict__ Wt, SharedU& sh) {
  int t = threadIdx.x;
  int g = idx >> 4, rem = idx & 15;
  int k0 = (rem & 3) * 64, n0 = (rem >> 2) * 64;
  const float* src = (g == 0) ? W0 : (Wc + (g - 1) * NDIM * NDIM);
  #pragma unroll
  for (int it = 0; it < 16; it++) {
    int e = t + 256 * it;
    int row = e >> 6, col = e & 63;
    sh.wt.tile[row][col] = src[(k0 + row) * NDIM + n0 + col];
  }
  __syncthreads();
  #pragma unroll
  for (int it = 0; it < 16; it++) {
    int e = t + 256 * it;
    int row = e >> 6, col = e & 63;
    Wt[(g * NDIM + n0 + row) * NDIM + k0 + col] = __float2bfloat16(sh.wt.tile[col][row]);
  }
}

// ---------------------------------------------------------------------------
// P1 task A: h0 GEMM row-tile rt (0..749): 4 waves, wave w = col quarter.
// h0t[mb][col][p] = relu(xb @ W0 + b0) stored transposed per dialogue.
__device__ __forceinline__ void gemm0_task(
    int rt, const __hip_bfloat16* __restrict__ A, const __hip_bfloat16* __restrict__ Wt,
    const float* __restrict__ bias, __hip_bfloat16* __restrict__ h0t) {
  int t = threadIdx.x;
  int ch = t >> 6, l = t & 63;
  int l15 = l & 15, lk = (l >> 4) * 8;
  int row = rt * 16 + l15;
  const short8* As = (const short8*)A;
  const short8* Bs = (const short8*)Wt;
  f32x4 acc[4];
  #pragma unroll
  for (int c = 0; c < 4; c++) acc[c] = (f32x4){0.f,0.f,0.f,0.f};
  #pragma unroll
  for (int k0 = 0; k0 < NDIM; k0 += 32) {
    short8 af = As[(row * NDIM + k0 + lk) >> 3];
    #pragma unroll
    for (int c = 0; c < 4; c++) {
      int col = ch * 64 + c * 16 + l15;
      short8 bf = Bs[(col * NDIM + k0 + lk) >> 3];
      acc[c] = __builtin_amdgcn_mfma_f32_16x16x32_bf16(af, bf, acc[c], 0, 0, 0);
    }
  }
  int node0 = rt * 16 + (l >> 4) * 4;   // 4-row group never straddles a dialogue
  int m = node0 / N_UTT;
  int i = node0 - m * N_UTT;
  int b = i / L_DIA, p0 = i - b * L_DIA;
  int mb = m * B_DIA + b;
  #pragma unroll
  for (int c = 0; c < 4; c++) {
    int col = ch * 64 + c * 16 + l15;
    bfpk4 pk;
    #pragma unroll
    for (int rr = 0; rr < 4; rr++)
      pk.h[rr] = __float2bfloat16(fmaxf(acc[c][rr] + bias[col], 0.f));
    *(uint2*)&h0t[((mb * NDIM + col) << 6) + p0] = pk.u;
  }
}

// P1 task B: graph builder for dialogue b: sim+cross+degree -> A_ext slabs.
// Waves 0..2 = modalities; wave 3 mostly idle.
__device__ __forceinline__ void graph_task(
    int b, const __hip_bfloat16* __restrict__ xn, __hip_bfloat16* __restrict__ Aext,
    SharedU& sh) {
  int t = threadIdx.x;
  int w = t >> 6, l = t & 63;
  int l15 = l & 15, lk = (l >> 4) * 8;
  const float inv_pi = 0.31830988618379067f;
  if (w < 3) {
    int m = w;
    int pm = (w + 1) % 3;
    int pairidx = (w == 0) ? 0 : (w == 1) ? 2 : 1;  // (0,1)->0 (1,2)->2 (2,0)->1
    int obase = m * N_UTT + b * L_DIA;
    int pbase = pm * N_UTT + b * L_DIA;
    const short8* xs = (const short8*)xn;
    int rowi[3];
    #pragma unroll
    for (int rt = 0; rt < 3; rt++) {
      int rr_ = 16 * rt + l15;
      rowi[rt] = (rr_ < L_DIA) ? rr_ : (L_DIA - 1);
    }
    f32x4 s[3][3], cacc[3];
    #pragma unroll
    for (int rt = 0; rt < 3; rt++) {
      cacc[rt] = (f32x4){0.f,0.f,0.f,0.f};
      #pragma unroll
      for (int ct = 0; ct < 3; ct++) s[rt][ct] = (f32x4){0.f,0.f,0.f,0.f};
    }
    for (int k0 = 0; k0 < NDIM; k0 += 32) {
      short8 own[3], par[3];
      #pragma unroll
      for (int rt = 0; rt < 3; rt++) own[rt] = xs[((obase + rowi[rt]) * NDIM + k0 + lk) >> 3];
      #pragma unroll
      for (int rt = 0; rt < 3; rt++) par[rt] = xs[((pbase + rowi[rt]) * NDIM + k0 + lk) >> 3];
      #pragma unroll
      for (int rt = 0; rt < 3; rt++) {
        #pragma unroll
        for (int ct = 0; ct < 3; ct++)
          s[rt][ct] = __builtin_amdgcn_mfma_f32_16x16x32_bf16(own[rt], own[ct], s[rt][ct], 0, 0, 0);
        cacc[rt] = __builtin_amdgcn_mfma_f32_16x16x32_bf16(own[rt], par[rt], cacc[rt], 0, 0, 0);
      }
    }
    #pragma unroll
    for (int rt = 0; rt < 3; rt++) {
      #pragma unroll
      for (int ct = 0; ct < 3; ct++) {
        #pragma unroll
        for (int rr = 0; rr < 4; rr++) {
          int row = 16 * rt + (l >> 4) * 4 + rr;
          int col = 16 * ct + l15;
          if (row < L_DIA && col < L_DIA) {
            float cs = fminf(fmaxf(s[rt][ct][rr] * 0.99999f, -1.f), 1.f);
            sh.gr.sim_s[m][row][col] = 1.0f - acosf(cs) * inv_pi;
          }
        }
      }
      #pragma unroll
      for (int rr = 0; rr < 4; rr++) {
        if (l15 == ((l >> 4) * 4 + rr)) {
          int dgi = 16 * rt + l15;
          if (dgi < L_DIA) {
            float cs = fminf(fmaxf(cacc[rt][rr] * 0.99999f, -1.f), 1.f);
            sh.gr.cr_s[pairidx][dgi] = 1.0f - acosf(cs) * inv_pi;
          }
        }
      }
    }
  }
  __syncthreads();
  if (t < 3 * L_DIA) {
    int mm = t / L_DIA, p = t - mm * L_DIA;
    float d = 0.f;
    #pragma unroll 10
    for (int q = 0; q < L_DIA; q++) d += sh.gr.sim_s[mm][p][q];
    if (mm == 0)      d += sh.gr.cr_s[0][p] + sh.gr.cr_s[1][p];
    else if (mm == 1) d += sh.gr.cr_s[0][p] + sh.gr.cr_s[2][p];
    else              d += sh.gr.cr_s[1][p] + sh.gr.cr_s[2][p];
    sh.gr.dinv_s[mm][p] = rsqrtf(d);
  }
  __syncthreads();
  if (w < 3) {
    int m = w;
    int pm0, pr0, pm1, pr1;
    if (m == 0)      { pm0 = 1; pr0 = 0; pm1 = 2; pr1 = 1; }
    else if (m == 1) { pm0 = 0; pr0 = 0; pm1 = 2; pr1 = 2; }
    else             { pm0 = 0; pr0 = 1; pm1 = 1; pr1 = 2; }
    int mb = m * B_DIA + b;
    unsigned int* Au = (unsigned int*)Aext;
    for (int e = l; e < 48 * 128; e += 64) {
      int row = e >> 7;
      int kp = (e & 127) * 2;
      bfpk2 pk; pk.u = 0;
      if (row < L_DIA) {
        #pragma unroll
        for (int jj = 0; jj < 2; jj++) {
          int k = kp + jj;
          float vv = 0.f;
          if (k < L_DIA) {
            vv = 0.9f * sh.gr.sim_s[m][row][k] * sh.gr.dinv_s[m][row] * sh.gr.dinv_s[m][k];
          } else if (k - 64 == row) {
            vv = 0.9f * sh.gr.cr_s[pr0][row] * sh.gr.dinv_s[m][row] * sh.gr.dinv_s[pm0][row];
          } else if (k - 128 == row) {
            vv = 0.9f * sh.gr.cr_s[pr1][row] * sh.gr.dinv_s[m][row] * sh.gr.dinv_s[pm1][row];
          } else if (k - 192 == row) {
            vv = 0.1f;
          }
          pk.h[jj] = __float2bfloat16(vv);
        }
      }
      Au[(mb * 48 + row) * 128 + (e & 127)] = pk.u;
    }
  }
}

// ---------------------------------------------------------------------------
// P2..P5 task: fused layer for slab mb: sup = A_ext @ [h_m;h_pm0;h_pm1;h0],
// then h_next = relu(theta*(sup@W) + (1-theta)*sup).
__device__ __forceinline__ void layer_task(
    int mb, bool last,
    const __hip_bfloat16* __restrict__ ht_in, const __hip_bfloat16* __restrict__ h0t,
    const __hip_bfloat16* __restrict__ Aext, const __hip_bfloat16* __restrict__ Wt,
    __hip_bfloat16* __restrict__ ht_out, float* __restrict__ out, float theta,
    SharedU& sh) {
  int m = mb / B_DIA, b = mb - m * B_DIA;
  int t = threadIdx.x, w = t >> 6, l = t & 63;
  int l15 = l & 15, lk = (l >> 4) * 8;
  int pm0, pm1;
  if (m == 0)      { pm0 = 1; pm1 = 2; }
  else if (m == 1) { pm0 = 0; pm1 = 2; }
  else             { pm0 = 0; pm1 = 1; }
  const __hip_bfloat16* srcs[4] = {
    ht_in + ((m   * B_DIA + b) << 14),
    ht_in + ((pm0 * B_DIA + b) << 14),
    ht_in + ((pm1 * B_DIA + b) << 14),
    h0t   + ((m   * B_DIA + b) << 14) };
  const short8* A8 = (const short8*)Aext;

  // ---- stage 1: sup = A_ext @ B_ext ----
  f32x4 acc[3][4];
  #pragma unroll
  for (int rt = 0; rt < 3; rt++)
    #pragma unroll
    for (int c = 0; c < 4; c++) acc[rt][c] = (f32x4){0.f,0.f,0.f,0.f};
  #pragma unroll
  for (int j = 0; j < 8; j++) {
    int k32 = (j & 1) * 32;
    short8 af[3];
    #pragma unroll
    for (int rt = 0; rt < 3; rt++)
      af[rt] = A8[((mb * 48 + rt * 16 + l15) * 256 + j * 32 + lk) >> 3];
    const short8* bp = (const short8*)srcs[j >> 1];
    #pragma unroll
    for (int c = 0; c < 4; c++) {
      int col = w * 64 + c * 16 + l15;
      short8 bf = bp[((col << 6) + k32 + lk) >> 3];
      #pragma unroll
      for (int rt = 0; rt < 3; rt++)
        acc[rt][c] = __builtin_amdgcn_mfma_f32_16x16x32_bf16(af[rt], bf, acc[rt][c], 0, 0, 0);
    }
  }
  #pragma unroll
  for (int rt = 0; rt < 3; rt++) {
    #pragma unroll
    for (int c = 0; c < 4; c++) {
      int col = w * 64 + c * 16 + l15;
      #pragma unroll
      for (int rr = 0; rr < 4; rr++) {
        int row = rt * 16 + (l >> 4) * 4 + rr;
        *((__hip_bfloat16*)&sh.ly.sup[row][col]) = __float2bfloat16(acc[rt][c][rr]);
      }
    }
  }
  __syncthreads();

  // ---- stage 2: o = sup @ W ----
  f32x4 o[3][4];
  #pragma unroll
  for (int rt = 0; rt < 3; rt++)
    #pragma unroll
    for (int c = 0; c < 4; c++) o[rt][c] = (f32x4){0.f,0.f,0.f,0.f};
  #pragma unroll
  for (int k0 = 0; k0 < NDIM; k0 += 32) {
    short8 af[3];
    #pragma unroll
    for (int rt = 0; rt < 3; rt++)
      af[rt] = *(const short8*)&sh.ly.sup[rt * 16 + l15][k0 + lk];
    #pragma unroll
    for (int c = 0; c < 4; c++) {
      int col = w * 64 + c * 16 + l15;
      short8 bf = *(const short8*)&Wt[col * NDIM + k0 + lk];
      #pragma unroll
      for (int rt = 0; rt < 3; rt++)
        o[rt][c] = __builtin_amdgcn_mfma_f32_16x16x32_bf16(af[rt], bf, o[rt][c], 0, 0, 0);
    }
  }
  float onemt = 1.f - theta;
  #pragma unroll
  for (int rt = 0; rt < 3; rt++) {
    int p0 = rt * 16 + (l >> 4) * 4;
    if (p0 >= L_DIA) continue;
    #pragma unroll
    for (int c = 0; c < 4; c++) {
      int col = w * 64 + c * 16 + l15;
      float vv[4];
      #pragma unroll
      for (int rr = 0; rr < 4; rr++) {
        float supv = __bfloat162float(*((__hip_bfloat16*)&sh.ly.sup[p0 + rr][col]));
        vv[rr] = fmaxf(theta * o[rt][c][rr] + onemt * supv, 0.f);
      }
      if (last) {
        #pragma unroll
        for (int rr = 0; rr < 4; rr++)
          out[(b * L_DIA + p0 + rr) * 1536 + m * 512 + 256 + col] = vv[rr];
      } else {
        bfpk4 pk;
        #pragma unroll
        for (int rr = 0; rr < 4; rr++) pk.h[rr] = __float2bfloat16(vv[rr]);
        *(uint2*)&ht_out[((mb * NDIM + col) << 6) + p0] = pk.u;
      }
    }
  }
}

// ---------------------------------------------------------------------------
__global__ __launch_bounds__(256, 2) void k_fused(
    const float* __restrict__ a, const float* __restrict__ v,
    const float* __restrict__ l, const float* __restrict__ qmask,
    const float* __restrict__ spk, const float* __restrict__ W0,
    const float* __restrict__ b0, const float* __restrict__ Wc,
    float* __restrict__ out,
    __hip_bfloat16* __restrict__ xb, __hip_bfloat16* __restrict__ xnb,
    __hip_bfloat16* __restrict__ h0t, __hip_bfloat16* __restrict__ htA,
    __hip_bfloat16* __restrict__ htB, __hip_bfloat16* __restrict__ Aext,
    __hip_bfloat16* __restrict__ Wt, unsigned int* __restrict__ bar) {
  __shared__ SharedU sh;

  // ---- P0: build_x rows (12000) + weight-transpose tiles (80) ----
  for (int task = blockIdx.x; task < NNODE + 80; task += NBLK) {
    if (task < NNODE) build_x_row(task, a, v, l, qmask, spk, out, xb, xnb, sh);
    else              wt_tile(task - NNODE, W0, Wc, Wt, sh);
    __syncthreads();
  }
  gsync(bar, bar + 1);

  // ---- P1: h0 GEMM (750) + graph builder (100) ----
  for (int task = blockIdx.x; task < 850; task += NBLK) {
    if (task < 750) gemm0_task(task, xb, Wt, b0, h0t);
    else            graph_task(task - 750, xnb, Aext, sh);
    __syncthreads();
  }
  gsync(bar, bar + 1);

  // ---- P2..P5: 4 GCN layers ----
  const float thetas[NLAYERS] = {0.40546510810816438f, 0.22314355131420976f,
                                 0.15415067982725836f, 0.11778303565638346f};
  const __hip_bfloat16* hin = h0t;
  for (int i = 0; i < NLAYERS; i++) {
    __hip_bfloat16* hout = (i & 1) ? htB : htA;
    bool last = (i == NLAYERS - 1);
    for (int task = blockIdx.x; task < 3 * B_DIA; task += NBLK) {
      layer_task(task, last, hin, h0t, Aext, Wt + (i + 1) * NDIM * NDIM,
                 hout, out, thetas[i], sh);
      __syncthreads();
    }
    hin = hout;
    if (i < NLAYERS - 1) gsync(bar, bar + 1);
  }
}

// ---------------------------------------------------------------------------
extern "C" void kernel_launch(void* const* d_in, const int* in_sizes, int n_in,
                              void* d_out, int out_size, void* d_ws, size_t ws_size,
                              hipStream_t stream) {
  const float* a     = (const float*)d_in[0];
  const float* v     = (const float*)d_in[1];
  const float* l     = (const float*)d_in[2];
  const float* qmask = (const float*)d_in[3];
  const float* spk   = (const float*)d_in[4];
  const float* W0    = (const float*)d_in[5];
  const float* b0    = (const float*)d_in[6];
  const float* Wc    = (const float*)d_in[7];
  float* out = (float*)d_out;
  float* ws  = (float*)d_ws;

  __hip_bfloat16* xb   = (__hip_bfloat16*)ws;                    // 1,536,000 fl
  __hip_bfloat16* xnb  = (__hip_bfloat16*)(ws + 1536000);        // 1,536,000
  __hip_bfloat16* h0t  = (__hip_bfloat16*)(ws + 3072000);        // 2,457,600
  __hip_bfloat16* htA  = (__hip_bfloat16*)(ws + 5529600);        // 2,457,600
  __hip_bfloat16* htB  = (__hip_bfloat16*)(ws + 7987200);        // 2,457,600
  __hip_bfloat16* Aext = (__hip_bfloat16*)(ws + 10444800);       // 1,843,200
  __hip_bfloat16* Wt   = (__hip_bfloat16*)(ws + 12288000);       //   163,840
  unsigned int*   bar  = (unsigned int*)(ws + 12451840);         // 4 uints

  hipMemsetAsync(bar, 0, 16, stream);
  k_fused<<<NBLK, 256, 0, stream>>>(a, v, l, qmask, spk, W0, b0, Wc, out,
                                    xb, xnb, h0t, htA, htB, Aext, Wt, bar);
}

// Round 7
// 182.805 us; speedup vs baseline: 2.7969x; 2.7969x over previous
//
#include <hip/hip_runtime.h>
#include <hip/hip_bf16.h>

#define N_UTT 4000
#define NDIM 256
#define B_DIA 100
#define L_DIA 40
#define NNODE 12000   // 3*N_UTT
#define NLAYERS 4

typedef __attribute__((ext_vector_type(8))) short short8;   // 8 bf16 (4 VGPRs)
typedef __attribute__((ext_vector_type(4))) float f32x4;    // MFMA acc

union bfpk2 { __hip_bfloat16 h[2]; unsigned int u; };
union bfpk4 { __hip_bfloat16 h[4]; uint2 u; };

// ---------------------------------------------------------------------------
// K_prep: blocks [0,12000) build x rows; blocks [12000,12080) transpose W.
__global__ void k_prep(const float* __restrict__ a, const float* __restrict__ v,
                       const float* __restrict__ l, const float* __restrict__ qmask,
                       const float* __restrict__ spk, const float* __restrict__ W0,
                       const float* __restrict__ Wc, float* __restrict__ out,
                       __hip_bfloat16* __restrict__ xb,
                       __hip_bfloat16* __restrict__ xnb,
                       __hip_bfloat16* __restrict__ Wt) {
  __shared__ float tile[64][65];      // wt path; build_x uses tile[0][0..3]
  int t = threadIdx.x;
  if (blockIdx.x < NNODE) {
    int r = blockIdx.x;
    int m = r / N_UTT;
    int i = r - m * N_UTT;
    float val;
    if (m == 0) val = a[i * NDIM + t];
    else if (m == 1) val = v[i * NDIM + t];
    else {
      int b = i / L_DIA, p = i - b * L_DIA;
      float q0 = qmask[p * (B_DIA * 2) + b * 2 + 0];
      float q1 = qmask[p * (B_DIA * 2) + b * 2 + 1];
      int s = (q1 > q0) ? 1 : 0;
      val = l[i * NDIM + t] + spk[s * NDIM + t];
    }
    out[i * 1536 + m * 512 + t] = val;           // x-part of final output
    xb[r * NDIM + t] = __float2bfloat16(val);
    float ss = val * val;
    #pragma unroll
    for (int off = 32; off > 0; off >>= 1) ss += __shfl_down(ss, off);
    int wid = t >> 6, lane = t & 63;
    if (lane == 0) tile[0][wid] = ss;
    __syncthreads();
    float inv = rsqrtf(tile[0][0] + tile[0][1] + tile[0][2] + tile[0][3]);
    xnb[r * NDIM + t] = __float2bfloat16(val * inv);
  } else {
    int idx = blockIdx.x - NNODE;     // 0..79
    int g = idx >> 4, rem = idx & 15;
    int k0 = (rem & 3) * 64, n0 = (rem >> 2) * 64;
    const float* src = (g == 0) ? W0 : (Wc + (g - 1) * NDIM * NDIM);
    #pragma unroll
    for (int it = 0; it < 16; it++) {
      int e = t + 256 * it;
      int row = e >> 6, col = e & 63;
      tile[row][col] = src[(k0 + row) * NDIM + n0 + col];
    }
    __syncthreads();
    #pragma unroll
    for (int it = 0; it < 16; it++) {
      int e = t + 256 * it;
      int row = e >> 6, col = e & 63;
      Wt[(g * NDIM + n0 + row) * NDIM + k0 + col] = __float2bfloat16(tile[col][row]);
    }
  }
}

// ---------------------------------------------------------------------------
// K_mid: blocks [0,750) = h0 GEMM row-tiles (4 waves, wave = col quarter);
//        blocks [750,850) = graph builder (sim+cross+degree -> A_ext slabs).
__global__ void k_mid(const __hip_bfloat16* __restrict__ xb,
                      const __hip_bfloat16* __restrict__ xnb,
                      const __hip_bfloat16* __restrict__ Wt,
                      const float* __restrict__ bias,
                      __hip_bfloat16* __restrict__ h0t,
                      __hip_bfloat16* __restrict__ Aext) {
  __shared__ float sim_s[3][L_DIA][41];
  __shared__ float cr_s[3][L_DIA];
  __shared__ float dinv_s[3][L_DIA];
  int t = threadIdx.x;
  int w = t >> 6, l = t & 63;
  int l15 = l & 15, lk = (l >> 4) * 8;

  if (blockIdx.x < 750) {
    // ---- h0 GEMM: h0t[mb][col][p] = relu(xb @ W0 + b0), transposed slabs ----
    int rt = blockIdx.x;
    int ch = w;
    int row = rt * 16 + l15;
    const short8* As = (const short8*)xb;
    const short8* Bs = (const short8*)Wt;
    f32x4 acc[4];
    #pragma unroll
    for (int c = 0; c < 4; c++) acc[c] = (f32x4){0.f,0.f,0.f,0.f};
    #pragma unroll
    for (int k0 = 0; k0 < NDIM; k0 += 32) {
      short8 af = As[(row * NDIM + k0 + lk) >> 3];
      #pragma unroll
      for (int c = 0; c < 4; c++) {
        int col = ch * 64 + c * 16 + l15;
        short8 bf = Bs[(col * NDIM + k0 + lk) >> 3];
        acc[c] = __builtin_amdgcn_mfma_f32_16x16x32_bf16(af, bf, acc[c], 0, 0, 0);
      }
    }
    int node0 = rt * 16 + (l >> 4) * 4;   // 4-row group never straddles a dialogue
    int m = node0 / N_UTT;
    int i = node0 - m * N_UTT;
    int b = i / L_DIA, p0 = i - b * L_DIA;
    int mb = m * B_DIA + b;
    #pragma unroll
    for (int c = 0; c < 4; c++) {
      int col = ch * 64 + c * 16 + l15;
      bfpk4 pk;
      #pragma unroll
      for (int rr = 0; rr < 4; rr++)
        pk.h[rr] = __float2bfloat16(fmaxf(acc[c][rr] + bias[col], 0.f));
      *(uint2*)&h0t[((mb * NDIM + col) << 6) + p0] = pk.u;
    }
    return;
  }

  // ---- graph builder for dialogue b ----
  int b = blockIdx.x - 750;
  const float inv_pi = 0.31830988618379067f;
  if (w < 3) {
    int m = w;
    int pm = (w + 1) % 3;
    int pairidx = (w == 0) ? 0 : (w == 1) ? 2 : 1;  // (0,1)->0 (1,2)->2 (2,0)->1
    int obase = m * N_UTT + b * L_DIA;
    int pbase = pm * N_UTT + b * L_DIA;
    const short8* xs = (const short8*)xnb;
    int rowi[3];
    #pragma unroll
    for (int rt = 0; rt < 3; rt++) {
      int rr_ = 16 * rt + l15;
      rowi[rt] = (rr_ < L_DIA) ? rr_ : (L_DIA - 1);
    }
    f32x4 s[3][3], cacc[3];
    #pragma unroll
    for (int rt = 0; rt < 3; rt++) {
      cacc[rt] = (f32x4){0.f,0.f,0.f,0.f};
      #pragma unroll
      for (int ct = 0; ct < 3; ct++) s[rt][ct] = (f32x4){0.f,0.f,0.f,0.f};
    }
    for (int k0 = 0; k0 < NDIM; k0 += 32) {
      short8 own[3], par[3];
      #pragma unroll
      for (int rt = 0; rt < 3; rt++) own[rt] = xs[((obase + rowi[rt]) * NDIM + k0 + lk) >> 3];
      #pragma unroll
      for (int rt = 0; rt < 3; rt++) par[rt] = xs[((pbase + rowi[rt]) * NDIM + k0 + lk) >> 3];
      #pragma unroll
      for (int rt = 0; rt < 3; rt++) {
        #pragma unroll
        for (int ct = 0; ct < 3; ct++)
          s[rt][ct] = __builtin_amdgcn_mfma_f32_16x16x32_bf16(own[rt], own[ct], s[rt][ct], 0, 0, 0);
        cacc[rt] = __builtin_amdgcn_mfma_f32_16x16x32_bf16(own[rt], par[rt], cacc[rt], 0, 0, 0);
      }
    }
    #pragma unroll
    for (int rt = 0; rt < 3; rt++) {
      #pragma unroll
      for (int ct = 0; ct < 3; ct++) {
        #pragma unroll
        for (int rr = 0; rr < 4; rr++) {
          int row = 16 * rt + (l >> 4) * 4 + rr;
          int col = 16 * ct + l15;
          if (row < L_DIA && col < L_DIA) {
            float cs = fminf(fmaxf(s[rt][ct][rr] * 0.99999f, -1.f), 1.f);
            sim_s[m][row][col] = 1.0f - acosf(cs) * inv_pi;
          }
        }
      }
      #pragma unroll
      for (int rr = 0; rr < 4; rr++) {
        if (l15 == ((l >> 4) * 4 + rr)) {
          int dgi = 16 * rt + l15;
          if (dgi < L_DIA) {
            float cs = fminf(fmaxf(cacc[rt][rr] * 0.99999f, -1.f), 1.f);
            cr_s[pairidx][dgi] = 1.0f - acosf(cs) * inv_pi;
          }
        }
      }
    }
  }
  __syncthreads();
  if (t < 3 * L_DIA) {
    int mm = t / L_DIA, p = t - mm * L_DIA;
    float d = 0.f;
    #pragma unroll 10
    for (int q = 0; q < L_DIA; q++) d += sim_s[mm][p][q];
    if (mm == 0)      d += cr_s[0][p] + cr_s[1][p];
    else if (mm == 1) d += cr_s[0][p] + cr_s[2][p];
    else              d += cr_s[1][p] + cr_s[2][p];
    dinv_s[mm][p] = rsqrtf(d);
  }
  __syncthreads();
  if (w < 3) {
    int m = w;
    int pm0, pr0, pm1, pr1;
    if (m == 0)      { pm0 = 1; pr0 = 0; pm1 = 2; pr1 = 1; }
    else if (m == 1) { pm0 = 0; pr0 = 0; pm1 = 2; pr1 = 2; }
    else             { pm0 = 0; pr0 = 1; pm1 = 1; pr1 = 2; }
    int mb = m * B_DIA + b;
    unsigned int* Au = (unsigned int*)Aext;
    for (int e = l; e < 48 * 128; e += 64) {
      int row = e >> 7;
      int kp = (e & 127) * 2;
      bfpk2 pk; pk.u = 0;
      if (row < L_DIA) {
        #pragma unroll
        for (int jj = 0; jj < 2; jj++) {
          int k = kp + jj;
          float vv = 0.f;
          if (k < L_DIA) {
            vv = 0.9f * sim_s[m][row][k] * dinv_s[m][row] * dinv_s[m][k];
          } else if (k - 64 == row) {
            vv = 0.9f * cr_s[pr0][row] * dinv_s[m][row] * dinv_s[pm0][row];
          } else if (k - 128 == row) {
            vv = 0.9f * cr_s[pr1][row] * dinv_s[m][row] * dinv_s[pm1][row];
          } else if (k - 192 == row) {
            vv = 0.1f;
          }
          pk.h[jj] = __float2bfloat16(vv);
        }
      }
      Au[(mb * 48 + row) * 128 + (e & 127)] = pk.u;
    }
  }
}

// ---------------------------------------------------------------------------
// K_layer: fused layer for slab mb: sup = A_ext @ [h_m;h_pm0;h_pm1;h0] (K=256),
// then h_next = relu(theta*(sup@W) + (1-theta)*sup).
// 512 thr = 8 waves; wave w owns cols [32w, 32w+32).
// LAST=0: writes ht_out (transposed slab); LAST=1: writes out h-slots (fp32).
template<int LAST>
__global__ __launch_bounds__(512) void k_layer(
    const __hip_bfloat16* __restrict__ ht_in,   // [300][256][64]
    const __hip_bfloat16* __restrict__ h0t,     // [300][256][64]
    const __hip_bfloat16* __restrict__ Aext,    // [300][48][256]
    const __hip_bfloat16* __restrict__ Wt,      // layer's [256][256] (col-major)
    __hip_bfloat16* __restrict__ ht_out,
    float* __restrict__ out, float theta) {
  int mb = blockIdx.x;
  int m = mb / B_DIA, b = mb - m * B_DIA;
  int t = threadIdx.x, w = t >> 6, l = t & 63;
  int l15 = l & 15, lk = (l >> 4) * 8;
  int pm0, pm1;
  if (m == 0)      { pm0 = 1; pm1 = 2; }
  else if (m == 1) { pm0 = 0; pm1 = 2; }
  else             { pm0 = 0; pm1 = 1; }
  const __hip_bfloat16* srcs[4] = {
    ht_in + ((m   * B_DIA + b) << 14),
    ht_in + ((pm0 * B_DIA + b) << 14),
    ht_in + ((pm1 * B_DIA + b) << 14),
    h0t   + ((m   * B_DIA + b) << 14) };
  const short8* A8 = (const short8*)Aext;

  // ---- stage 1: sup = A_ext @ B_ext (this wave: 32 cols) ----
  f32x4 acc[3][2];
  #pragma unroll
  for (int rt = 0; rt < 3; rt++)
    #pragma unroll
    for (int c = 0; c < 2; c++) acc[rt][c] = (f32x4){0.f,0.f,0.f,0.f};
  #pragma unroll
  for (int j = 0; j < 8; j++) {          // k0 = 32*j; source block j>>1
    int k32 = (j & 1) * 32;
    short8 af[3];
    #pragma unroll
    for (int rt = 0; rt < 3; rt++)
      af[rt] = A8[((mb * 48 + rt * 16 + l15) * 256 + j * 32 + lk) >> 3];
    const short8* bp = (const short8*)srcs[j >> 1];
    #pragma unroll
    for (int c = 0; c < 2; c++) {
      int col = w * 32 + c * 16 + l15;
      short8 bf = bp[((col << 6) + k32 + lk) >> 3];
      #pragma unroll
      for (int rt = 0; rt < 3; rt++)
        acc[rt][c] = __builtin_amdgcn_mfma_f32_16x16x32_bf16(af[rt], bf, acc[rt][c], 0, 0, 0);
    }
  }
  __shared__ alignas(16) __hip_bfloat16 sup[48][264];   // 264*2=528B rows, 16B-aligned
  #pragma unroll
  for (int rt = 0; rt < 3; rt++) {
    #pragma unroll
    for (int c = 0; c < 2; c++) {
      int col = w * 32 + c * 16 + l15;
      #pragma unroll
      for (int rr = 0; rr < 4; rr++) {
        int row = rt * 16 + (l >> 4) * 4 + rr;
        sup[row][col] = __float2bfloat16(acc[rt][c][rr]);
      }
    }
  }
  __syncthreads();

  // ---- stage 2: o = sup @ W (this wave: 32 cols) ----
  f32x4 o[3][2];
  #pragma unroll
  for (int rt = 0; rt < 3; rt++)
    #pragma unroll
    for (int c = 0; c < 2; c++) o[rt][c] = (f32x4){0.f,0.f,0.f,0.f};
  #pragma unroll
  for (int k0 = 0; k0 < NDIM; k0 += 32) {
    short8 af[3];
    #pragma unroll
    for (int rt = 0; rt < 3; rt++)
      af[rt] = *(const short8*)&sup[rt * 16 + l15][k0 + lk];
    #pragma unroll
    for (int c = 0; c < 2; c++) {
      int col = w * 32 + c * 16 + l15;
      short8 bf = *(const short8*)&Wt[col * NDIM + k0 + lk];
      #pragma unroll
      for (int rt = 0; rt < 3; rt++)
        o[rt][c] = __builtin_amdgcn_mfma_f32_16x16x32_bf16(af[rt], bf, o[rt][c], 0, 0, 0);
    }
  }
  float onemt = 1.f - theta;
  #pragma unroll
  for (int rt = 0; rt < 3; rt++) {
    int p0 = rt * 16 + (l >> 4) * 4;
    if (p0 >= L_DIA) continue;
    #pragma unroll
    for (int c = 0; c < 2; c++) {
      int col = w * 32 + c * 16 + l15;
      float vv[4];
      #pragma unroll
      for (int rr = 0; rr < 4; rr++) {
        float supv = __bfloat162float(sup[p0 + rr][col]);
        vv[rr] = fmaxf(theta * o[rt][c][rr] + onemt * supv, 0.f);
      }
      if (LAST) {
        #pragma unroll
        for (int rr = 0; rr < 4; rr++)
          out[(b * L_DIA + p0 + rr) * 1536 + m * 512 + 256 + col] = vv[rr];
      } else {
        bfpk4 pk;
        #pragma unroll
        for (int rr = 0; rr < 4; rr++) pk.h[rr] = __float2bfloat16(vv[rr]);
        *(uint2*)&ht_out[((mb * NDIM + col) << 6) + p0] = pk.u;
      }
    }
  }
}

// ---------------------------------------------------------------------------
extern "C" void kernel_launch(void* const* d_in, const int* in_sizes, int n_in,
                              void* d_out, int out_size, void* d_ws, size_t ws_size,
                              hipStream_t stream) {
  const float* a     = (const float*)d_in[0];
  const float* v     = (const float*)d_in[1];
  const float* l     = (const float*)d_in[2];
  const float* qmask = (const float*)d_in[3];
  const float* spk   = (const float*)d_in[4];
  const float* W0    = (const float*)d_in[5];
  const float* b0    = (const float*)d_in[6];
  const float* Wc    = (const float*)d_in[7];
  float* out = (float*)d_out;
  float* ws  = (float*)d_ws;

  __hip_bfloat16* xb   = (__hip_bfloat16*)ws;                    // 1,536,000 fl
  __hip_bfloat16* xnb  = (__hip_bfloat16*)(ws + 1536000);        // 1,536,000
  __hip_bfloat16* h0t  = (__hip_bfloat16*)(ws + 3072000);        // 2,457,600
  __hip_bfloat16* htA  = (__hip_bfloat16*)(ws + 5529600);        // 2,457,600
  __hip_bfloat16* htB  = (__hip_bfloat16*)(ws + 7987200);        // 2,457,600
  __hip_bfloat16* Aext = (__hip_bfloat16*)(ws + 10444800);       // 1,843,200
  __hip_bfloat16* Wt   = (__hip_bfloat16*)(ws + 12288000);       //   163,840
  // total 12,451,840 fl = 49.8 MB

  k_prep<<<NNODE + 80, 256, 0, stream>>>(a, v, l, qmask, spk, W0, Wc, out, xb, xnb, Wt);
  k_mid<<<850, 256, 0, stream>>>(xb, xnb, Wt, b0, h0t, Aext);

  const float thetas[NLAYERS] = {0.40546510810816438f, 0.22314355131420976f,
                                 0.15415067982725836f, 0.11778303565638346f};
  const __hip_bfloat16* hcur = h0t;
  __hip_bfloat16* houts[NLAYERS] = {htA, htB, htA, nullptr};
  for (int i = 0; i < NLAYERS; i++) {
    if (i < NLAYERS - 1) {
      k_layer<0><<<3 * B_DIA, 512, 0, stream>>>(
          hcur, h0t, Aext, Wt + (i + 1) * NDIM * NDIM, houts[i], nullptr, thetas[i]);
      hcur = houts[i];
    } else {
      k_layer<1><<<3 * B_DIA, 512, 0, stream>>>(
          hcur, h0t, Aext, Wt + (i + 1) * NDIM * NDIM, nullptr, out, thetas[i]);
    }
  }
}

// Round 8
// 78.052 us; speedup vs baseline: 6.5506x; 2.3421x over previous
//
#include <hip/hip_runtime.h>
#include <hip/hip_bf16.h>

#define N_UTT 4000
#define NDIM 256
#define B_DIA 100
#define L_DIA 40
#define NLAYERS 4

typedef __attribute__((ext_vector_type(8))) short short8;   // 8 bf16 (4 VGPRs)
typedef __attribute__((ext_vector_type(4))) float f32x4;    // MFMA acc

union bfpk4 { __hip_bfloat16 h[4]; uint2 u; };

// ---------------------------------------------------------------------------
// K_wt: weight transpose+bf16 via LDS tile: Wt[g][n][k] = W_g[k][n]
__global__ void k_wt(const float* __restrict__ W0, const float* __restrict__ Wc,
                     __hip_bfloat16* __restrict__ Wt) {
  int k0 = blockIdx.x * 64, n0 = blockIdx.y * 64, g = blockIdx.z;
  int t = threadIdx.x;
  const float* src = (g == 0) ? W0 : (Wc + (g - 1) * NDIM * NDIM);
  __shared__ float tile[64][65];
  #pragma unroll
  for (int it = 0; it < 16; it++) {
    int e = t + 256 * it;
    int row = e >> 6, col = e & 63;
    tile[row][col] = src[(k0 + row) * NDIM + n0 + col];
  }
  __syncthreads();
  #pragma unroll
  for (int it = 0; it < 16; it++) {
    int e = t + 256 * it;
    int row = e >> 6, col = e & 63;
    Wt[(g * NDIM + n0 + row) * NDIM + k0 + col] = __float2bfloat16(tile[col][row]);
  }
}

// ---------------------------------------------------------------------------
// K_main: one block per dialogue. Full network LDS-resident.
//  xls  [3][40][264] : x bf16 (phases A-C), then sup bf16 (layers)
//  hls  [3][256][40] : h transposed [col][row] (stage-1 B operand, b128 2-way-free)
//  sext [3][40][136] : A_ext bf16, K=128: k<40 = S', k=40+p diag c0', k=80+p diag c1'
__global__ __launch_bounds__(512, 1) void k_main(
    const float* __restrict__ a, const float* __restrict__ v,
    const float* __restrict__ lf, const float* __restrict__ qmask,
    const float* __restrict__ spk, const float* __restrict__ b0,
    const __hip_bfloat16* __restrict__ Wt, float* __restrict__ out) {
  __shared__ __hip_bfloat16 xls[3][L_DIA][264];    // 63,360 B
  __shared__ __hip_bfloat16 hls[3][NDIM][L_DIA];   // 61,440 B
  __shared__ __hip_bfloat16 sext[3][L_DIA][136];   // 32,640 B
  __shared__ float invn[120];
  __shared__ float dinv[120];
  __shared__ float psum[120][4];

  int b = blockIdx.x;
  int t = threadIdx.x;
  int w = t >> 6, ln = t & 63;
  int l15 = ln & 15, lk = (ln >> 4) * 8;
  const float inv_pi = 0.31830988618379067f;

  // ---- phase A: zero sext; build x rows; write out-x; x -> xls bf16 ----
  {
    unsigned int* sz = (unsigned int*)&sext[0][0][0];
    #pragma unroll
    for (int e = t; e < 3 * L_DIA * 136 / 2; e += 512) sz[e] = 0u;
  }
  for (int e = t; e < 120 * 64; e += 512) {
    int r = e >> 6, c4 = e & 63;
    int m = r / L_DIA, p = r - m * L_DIA;
    int i = b * L_DIA + p;
    float4 val;
    if (m == 0)      val = ((const float4*)a)[i * 64 + c4];
    else if (m == 1) val = ((const float4*)v)[i * 64 + c4];
    else {
      val = ((const float4*)lf)[i * 64 + c4];
      float q0 = qmask[(p * B_DIA + b) * 2 + 0];
      float q1 = qmask[(p * B_DIA + b) * 2 + 1];
      int s = (q1 > q0) ? 1 : 0;
      float4 sv = ((const float4*)spk)[s * 64 + c4];
      val.x += sv.x; val.y += sv.y; val.z += sv.z; val.w += sv.w;
    }
    ((float4*)out)[i * 384 + m * 128 + c4] = val;     // x-part of output
    bfpk4 pk;
    pk.h[0] = __float2bfloat16(val.x); pk.h[1] = __float2bfloat16(val.y);
    pk.h[2] = __float2bfloat16(val.z); pk.h[3] = __float2bfloat16(val.w);
    *(uint2*)&xls[m][p][c4 * 4] = pk.u;
  }
  __syncthreads();

  // ---- row inverse norms ----
  if (t < 480) {
    int r = t >> 2, q4 = t & 3;
    int m = r / L_DIA, p = r - m * L_DIA;
    float s = 0.f;
    #pragma unroll
    for (int j = 0; j < 64; j++) {
      float xv = __bfloat162float(xls[m][p][q4 * 64 + j]);
      s += xv * xv;
    }
    psum[r][q4] = s;
  }
  __syncthreads();
  if (t < 120) invn[t] = rsqrtf(psum[t][0] + psum[t][1] + psum[t][2] + psum[t][3]);
  __syncthreads();

  // ---- phase B: sim (27 self tiles) + cross diagonals (9 pair tiles) ----
  #pragma unroll
  for (int it = 0; it < 5; it++) {
    int tau = w + 8 * it;
    if (tau < 36) {
      int mA, mB, rt, ct, isdiag = 0, slotA = 0, slotB = 0;
      if (tau < 27) {
        mA = tau / 9; int rc = tau - mA * 9; rt = rc / 3; ct = rc - rt * 3; mB = mA;
      } else {
        int pi = (tau - 27) / 3; rt = (tau - 27) - pi * 3; ct = rt;
        mA = (pi == 2) ? 1 : 0; mB = (pi == 0) ? 1 : 2;
        slotA = (pi == 0) ? 40 : 80; slotB = (pi == 2) ? 80 : 40;
        isdiag = 1;
      }
      int arow = rt * 16 + l15; if (arow > 39) arow = 39;
      int bcol = ct * 16 + l15; if (bcol > 39) bcol = 39;
      f32x4 acc = {0.f, 0.f, 0.f, 0.f};
      #pragma unroll
      for (int k0 = 0; k0 < NDIM; k0 += 32) {
        short8 af = *(const short8*)&xls[mA][arow][k0 + lk];
        short8 bf = *(const short8*)&xls[mB][bcol][k0 + lk];
        acc = __builtin_amdgcn_mfma_f32_16x16x32_bf16(af, bf, acc, 0, 0, 0);
      }
      #pragma unroll
      for (int rr = 0; rr < 4; rr++) {
        int row = rt * 16 + (ln >> 4) * 4 + rr;
        int col = ct * 16 + l15;
        if (!isdiag) {
          if (row < 40 && col < 40) {
            float cs = acc[rr] * invn[mA * 40 + row] * invn[mA * 40 + col] * 0.99999f;
            cs = fminf(fmaxf(cs, -1.f), 1.f);
            sext[mA][row][col] = __float2bfloat16(1.f - acosf(cs) * inv_pi);
          }
        } else {
          if (l15 == ((ln >> 4) * 4 + rr) && row < 40) {
            float cs = acc[rr] * invn[mA * 40 + row] * invn[mB * 40 + row] * 0.99999f;
            cs = fminf(fmaxf(cs, -1.f), 1.f);
            __hip_bfloat16 vv = __float2bfloat16(1.f - acosf(cs) * inv_pi);
            sext[mA][row][slotA + row] = vv;
            sext[mB][row][slotB + row] = vv;
          }
        }
      }
    }
  }
  __syncthreads();

  // ---- degrees -> dinv ----
  if (t < 120) {
    int m = t / 40, p = t - m * 40;
    float d = 0.f;
    #pragma unroll 10
    for (int q = 0; q < 40; q++) d += __bfloat162float(sext[m][p][q]);
    d += __bfloat162float(sext[m][p][40 + p]) + __bfloat162float(sext[m][p][80 + p]);
    dinv[t] = rsqrtf(d);
  }
  __syncthreads();
  // ---- normalize sext in place (fold 0.9 = 1-ALPHA) ----
  for (int e = t; e < 5040; e += 512) {
    if (e < 4800) {
      int m = e / 1600, rem = e - m * 1600;
      int p = rem / 40, q = rem - p * 40;
      sext[m][p][q] = __float2bfloat16(
          __bfloat162float(sext[m][p][q]) * 0.9f * dinv[m * 40 + p] * dinv[m * 40 + q]);
    } else {
      int idx = e - 4800;
      int m = idx / 80, j = idx - m * 80;
      int which = j / 40, p = j - which * 40;
      int pmx = which ? ((m == 2) ? 1 : 2) : ((m == 0) ? 1 : 0);
      int k = 40 * (1 + which) + p;
      sext[m][p][k] = __float2bfloat16(
          __bfloat162float(sext[m][p][k]) * 0.9f * dinv[m * 40 + p] * dinv[pmx * 40 + p]);
    }
  }
  __syncthreads();

  // ---- phase C: h0 = relu(x @ W0 + b0) -> hls (transposed) + h0 regs ----
  uint2 h0r[9][2];
  #pragma unroll
  for (int s = 0; s < 9; s++) {
    int m = s / 3, rt = s - m * 3;
    int arow = rt * 16 + l15; if (arow > 39) arow = 39;
    int p0 = rt * 16 + (ln >> 4) * 4;
    #pragma unroll
    for (int c = 0; c < 2; c++) {
      int col = w * 32 + c * 16 + l15;
      f32x4 acc = {0.f, 0.f, 0.f, 0.f};
      #pragma unroll
      for (int k0 = 0; k0 < NDIM; k0 += 32) {
        short8 af = *(const short8*)&xls[m][arow][k0 + lk];
        short8 bf = *(const short8*)&Wt[col * NDIM + k0 + lk];
        acc = __builtin_amdgcn_mfma_f32_16x16x32_bf16(af, bf, acc, 0, 0, 0);
      }
      float bias = b0[col];
      bfpk4 pk;
      #pragma unroll
      for (int rr = 0; rr < 4; rr++)
        pk.h[rr] = __float2bfloat16(fmaxf(acc[rr] + bias, 0.f));
      h0r[s][c] = pk.u;
      if (p0 < 40) *(uint2*)&hls[m][col][p0] = pk.u;
    }
  }
  __syncthreads();

  // ---- 4 GCN layers, fully LDS-resident ----
  const float thetas[NLAYERS] = {0.40546510810816438f, 0.22314355131420976f,
                                 0.15415067982725836f, 0.11778303565638346f};
  #pragma unroll
  for (int li = 0; li < NLAYERS; li++) {
    float th = thetas[li], onemt = 1.f - th;
    const __hip_bfloat16* Wl = Wt + (li + 1) * NDIM * NDIM;
    f32x4 supreg[9][2];
    // stage 1: sup = S_ext @ [h_m; h_pm0; h_pm1] + 0.1*h0  -> xls (bf16) + regs
    #pragma unroll
    for (int s = 0; s < 9; s++) {
      int m = s / 3, rt = s - m * 3;
      int pm0 = (m == 0) ? 1 : 0;
      int pm1 = (m == 2) ? 1 : 2;
      int arow = rt * 16 + l15; if (arow > 39) arow = 39;
      int p0 = rt * 16 + (ln >> 4) * 4;
      #pragma unroll
      for (int c = 0; c < 2; c++) {
        int col = w * 32 + c * 16 + l15;
        f32x4 acc = {0.f, 0.f, 0.f, 0.f};
        #pragma unroll
        for (int j = 0; j < 4; j++) {
          int kk = j * 32 + lk;
          int srcm, brow;
          if (kk < 40)       { srcm = m;   brow = kk; }
          else if (kk < 80)  { srcm = pm0; brow = kk - 40; }
          else if (kk < 120) { srcm = pm1; brow = kk - 80; }
          else               { srcm = m;   brow = 0; }     // sext zero there
          short8 af = *(const short8*)&sext[m][arow][j * 32 + lk];
          short8 bf = *(const short8*)&hls[srcm][col][brow];
          acc = __builtin_amdgcn_mfma_f32_16x16x32_bf16(af, bf, acc, 0, 0, 0);
        }
        bfpk4 h0p; h0p.u = h0r[s][c];
        #pragma unroll
        for (int rr = 0; rr < 4; rr++)
          acc[rr] += 0.1f * __bfloat162float(h0p.h[rr]);
        supreg[s][c] = acc;
        if (p0 < 40) {
          #pragma unroll
          for (int rr = 0; rr < 4; rr++)
            xls[m][p0 + rr][col] = __float2bfloat16(acc[rr]);
        }
      }
    }
    __syncthreads();
    // stage 2: h_new = relu(theta*(sup@W) + (1-theta)*sup)
    #pragma unroll
    for (int s = 0; s < 9; s++) {
      int m = s / 3, rt = s - m * 3;
      int arow = rt * 16 + l15; if (arow > 39) arow = 39;
      int p0 = rt * 16 + (ln >> 4) * 4;
      #pragma unroll
      for (int c = 0; c < 2; c++) {
        int col = w * 32 + c * 16 + l15;
        f32x4 acc = {0.f, 0.f, 0.f, 0.f};
        #pragma unroll
        for (int k0 = 0; k0 < NDIM; k0 += 32) {
          short8 af = *(const short8*)&xls[m][arow][k0 + lk];
          short8 bf = *(const short8*)&Wl[col * NDIM + k0 + lk];
          acc = __builtin_amdgcn_mfma_f32_16x16x32_bf16(af, bf, acc, 0, 0, 0);
        }
        if (p0 < 40) {
          if (li < NLAYERS - 1) {
            bfpk4 pk;
            #pragma unroll
            for (int rr = 0; rr < 4; rr++)
              pk.h[rr] = __float2bfloat16(
                  fmaxf(th * acc[rr] + onemt * supreg[s][c][rr], 0.f));
            *(uint2*)&hls[m][col][p0] = pk.u;
          } else {
            #pragma unroll
            for (int rr = 0; rr < 4; rr++)
              out[(b * L_DIA + p0 + rr) * 1536 + m * 512 + 256 + col] =
                  fmaxf(th * acc[rr] + onemt * supreg[s][c][rr], 0.f);
          }
        }
      }
    }
    __syncthreads();
  }
}

// ---------------------------------------------------------------------------
extern "C" void kernel_launch(void* const* d_in, const int* in_sizes, int n_in,
                              void* d_out, int out_size, void* d_ws, size_t ws_size,
                              hipStream_t stream) {
  const float* a     = (const float*)d_in[0];
  const float* v     = (const float*)d_in[1];
  const float* lf    = (const float*)d_in[2];
  const float* qmask = (const float*)d_in[3];
  const float* spk   = (const float*)d_in[4];
  const float* W0    = (const float*)d_in[5];
  const float* b0    = (const float*)d_in[6];
  const float* Wc    = (const float*)d_in[7];
  float* out = (float*)d_out;

  __hip_bfloat16* Wt = (__hip_bfloat16*)d_ws;   // 5*256*256 bf16 = 640 KB

  k_wt<<<dim3(4, 4, 5), 256, 0, stream>>>(W0, Wc, Wt);
  k_main<<<B_DIA, 512, 0, stream>>>(a, v, lf, qmask, spk, b0, Wt, out);
}

// Round 9
// 63.628 us; speedup vs baseline: 8.0355x; 1.2267x over previous
//
#include <hip/hip_runtime.h>
#include <hip/hip_bf16.h>

#define N_UTT 4000
#define NDIM 256
#define B_DIA 100
#define L_DIA 40
#define NLAYERS 4

typedef __attribute__((ext_vector_type(8))) short short8;   // 8 bf16 (4 VGPRs)
typedef __attribute__((ext_vector_type(4))) float f32x4;    // MFMA acc

union bfpk4 { __hip_bfloat16 h[4]; uint2 u; };

static __device__ __forceinline__ float bf2f(__hip_bfloat16 h) {
  union { float f; unsigned u; } x;
  x.u = ((unsigned)*(unsigned short*)&h) << 16;
  return x.f;
}

// ---------------------------------------------------------------------------
// K_wt: weight transpose+bf16 via LDS tile: Wt[g][n][k] = W_g[k][n]
__global__ void k_wt(const float* __restrict__ W0, const float* __restrict__ Wc,
                     __hip_bfloat16* __restrict__ Wt) {
  int k0 = blockIdx.x * 64, n0 = blockIdx.y * 64, g = blockIdx.z;
  int t = threadIdx.x;
  const float* src = (g == 0) ? W0 : (Wc + (g - 1) * NDIM * NDIM);
  __shared__ float tile[64][65];
  #pragma unroll
  for (int it = 0; it < 16; it++) {
    int e = t + 256 * it;
    int row = e >> 6, col = e & 63;
    tile[row][col] = src[(k0 + row) * NDIM + n0 + col];
  }
  __syncthreads();
  #pragma unroll
  for (int it = 0; it < 16; it++) {
    int e = t + 256 * it;
    int row = e >> 6, col = e & 63;
    Wt[(g * NDIM + n0 + row) * NDIM + k0 + col] = __float2bfloat16(tile[col][row]);
  }
}

// ---------------------------------------------------------------------------
// K_main: one block per dialogue; whole network LDS-resident; k-outer
// register-blocked MFMA (af[9] x bf[2] -> 18 MFMA per k-step).
__global__ __launch_bounds__(512, 1) void k_main(
    const float* __restrict__ a, const float* __restrict__ v,
    const float* __restrict__ lf, const float* __restrict__ qmask,
    const float* __restrict__ spk, const float* __restrict__ b0,
    const __hip_bfloat16* __restrict__ Wt, float* __restrict__ out) {
  __shared__ __hip_bfloat16 xls[3][L_DIA][264];    // x, then sup   (63,360 B)
  __shared__ __hip_bfloat16 hls[3][NDIM][L_DIA];   // h transposed  (61,440 B)
  __shared__ __hip_bfloat16 sext[3][L_DIA][136];   // A_ext K=128   (32,640 B)
  __shared__ float invn[120];
  __shared__ float dinv[120];
  __shared__ float psum[120][4];

  int b = blockIdx.x;
  int t = threadIdx.x;
  int w = t >> 6, ln = t & 63;
  int l15 = ln & 15, lk = (ln >> 4) * 8;
  const float inv_pi = 0.31830988618379067f;

  int arows[3], cols[2];
  #pragma unroll
  for (int rt = 0; rt < 3; rt++) {
    int rr_ = rt * 16 + l15;
    arows[rt] = (rr_ < L_DIA) ? rr_ : (L_DIA - 1);
  }
  #pragma unroll
  for (int c = 0; c < 2; c++) cols[c] = w * 32 + c * 16 + l15;

  // ---- phase A: zero sext; build x; write out-x; x -> xls bf16 ----
  {
    unsigned int* sz = (unsigned int*)&sext[0][0][0];
    #pragma unroll
    for (int e = t; e < 3 * L_DIA * 136 / 2; e += 512) sz[e] = 0u;
  }
  for (int e = t; e < 120 * 64; e += 512) {
    int r = e >> 6, c4 = e & 63;
    int m = r / L_DIA, p = r - m * L_DIA;
    int i = b * L_DIA + p;
    float4 val;
    if (m == 0)      val = ((const float4*)a)[i * 64 + c4];
    else if (m == 1) val = ((const float4*)v)[i * 64 + c4];
    else {
      val = ((const float4*)lf)[i * 64 + c4];
      float q0 = qmask[(p * B_DIA + b) * 2 + 0];
      float q1 = qmask[(p * B_DIA + b) * 2 + 1];
      int s = (q1 > q0) ? 1 : 0;
      float4 sv = ((const float4*)spk)[s * 64 + c4];
      val.x += sv.x; val.y += sv.y; val.z += sv.z; val.w += sv.w;
    }
    ((float4*)out)[i * 384 + m * 128 + c4] = val;
    bfpk4 pk;
    pk.h[0] = __float2bfloat16(val.x); pk.h[1] = __float2bfloat16(val.y);
    pk.h[2] = __float2bfloat16(val.z); pk.h[3] = __float2bfloat16(val.w);
    *(uint2*)&xls[m][p][c4 * 4] = pk.u;
  }
  __syncthreads();

  // ---- row inverse norms (vectorized) ----
  if (t < 480) {
    int r = t >> 2, q4 = t & 3;
    int m = r / L_DIA, p = r - m * L_DIA;
    float s = 0.f;
    #pragma unroll
    for (int jj = 0; jj < 8; jj++) {
      short8 vv = *(const short8*)&xls[m][p][q4 * 64 + jj * 8];
      #pragma unroll
      for (int e = 0; e < 8; e++) {
        union { float f; unsigned u; } x;
        x.u = ((unsigned)(unsigned short)vv[e]) << 16;
        s += x.f * x.f;
      }
    }
    psum[r][q4] = s;
  }
  __syncthreads();
  if (t < 120) invn[t] = rsqrtf(psum[t][0] + psum[t][1] + psum[t][2] + psum[t][3]);
  __syncthreads();

  // ---- phase B: wave-role split: w<3 self-sim 3x3 (A==B frags);
  //                                w in 3..5 pair diagonals ----
  if (w < 3) {
    int mA = w;
    f32x4 sacc[3][3];
    #pragma unroll
    for (int rt = 0; rt < 3; rt++)
      #pragma unroll
      for (int ct = 0; ct < 3; ct++) sacc[rt][ct] = (f32x4){0.f,0.f,0.f,0.f};
    #pragma unroll
    for (int k0 = 0; k0 < NDIM; k0 += 32) {
      short8 fr[3];
      #pragma unroll
      for (int rt = 0; rt < 3; rt++)
        fr[rt] = *(const short8*)&xls[mA][arows[rt]][k0 + lk];
      #pragma unroll
      for (int rt = 0; rt < 3; rt++)
        #pragma unroll
        for (int ct = 0; ct < 3; ct++)
          sacc[rt][ct] = __builtin_amdgcn_mfma_f32_16x16x32_bf16(fr[rt], fr[ct], sacc[rt][ct], 0, 0, 0);
    }
    #pragma unroll
    for (int rt = 0; rt < 3; rt++)
      #pragma unroll
      for (int ct = 0; ct < 3; ct++)
        #pragma unroll
        for (int rr = 0; rr < 4; rr++) {
          int row = rt * 16 + (ln >> 4) * 4 + rr;
          int col = ct * 16 + l15;
          if (row < L_DIA && col < L_DIA) {
            float cs = sacc[rt][ct][rr] * invn[mA * 40 + row] * invn[mA * 40 + col] * 0.99999f;
            cs = fminf(fmaxf(cs, -1.f), 1.f);
            sext[mA][row][col] = __float2bfloat16(1.f - acosf(cs) * inv_pi);
          }
        }
  } else if (w < 6) {
    int pi = w - 3;
    int mA = (pi == 2) ? 1 : 0, mB = (pi == 0) ? 1 : 2;
    int slotA = (pi == 0) ? 40 : 80, slotB = (pi == 2) ? 80 : 40;
    f32x4 dacc[3];
    #pragma unroll
    for (int rt = 0; rt < 3; rt++) dacc[rt] = (f32x4){0.f,0.f,0.f,0.f};
    #pragma unroll
    for (int k0 = 0; k0 < NDIM; k0 += 32) {
      short8 frA[3], frB[3];
      #pragma unroll
      for (int rt = 0; rt < 3; rt++) {
        frA[rt] = *(const short8*)&xls[mA][arows[rt]][k0 + lk];
        frB[rt] = *(const short8*)&xls[mB][arows[rt]][k0 + lk];
      }
      #pragma unroll
      for (int rt = 0; rt < 3; rt++)
        dacc[rt] = __builtin_amdgcn_mfma_f32_16x16x32_bf16(frA[rt], frB[rt], dacc[rt], 0, 0, 0);
    }
    #pragma unroll
    for (int rt = 0; rt < 3; rt++)
      #pragma unroll
      for (int rr = 0; rr < 4; rr++) {
        int row = rt * 16 + (ln >> 4) * 4 + rr;
        if (l15 == ((ln >> 4) * 4 + rr) && row < L_DIA) {
          float cs = dacc[rt][rr] * invn[mA * 40 + row] * invn[mB * 40 + row] * 0.99999f;
          cs = fminf(fmaxf(cs, -1.f), 1.f);
          __hip_bfloat16 vv = __float2bfloat16(1.f - acosf(cs) * inv_pi);
          sext[mA][row][slotA + row] = vv;
          sext[mB][row][slotB + row] = vv;
        }
      }
  }
  __syncthreads();

  // ---- degrees -> dinv ----
  if (t < 120) {
    int m = t / 40, p = t - m * 40;
    float d = 0.f;
    #pragma unroll 10
    for (int q = 0; q < 40; q++) d += bf2f(sext[m][p][q]);
    d += bf2f(sext[m][p][40 + p]) + bf2f(sext[m][p][80 + p]);
    dinv[t] = rsqrtf(d);
  }
  __syncthreads();
  // ---- normalize sext in place (fold 0.9) ----
  for (int e = t; e < 5040; e += 512) {
    if (e < 4800) {
      int m = e / 1600, rem = e - m * 1600;
      int p = rem / 40, q = rem - p * 40;
      sext[m][p][q] = __float2bfloat16(
          bf2f(sext[m][p][q]) * 0.9f * dinv[m * 40 + p] * dinv[m * 40 + q]);
    } else {
      int idx = e - 4800;
      int m = idx / 80, j = idx - m * 80;
      int which = j / 40, p = j - which * 40;
      int pmx = which ? ((m == 2) ? 1 : 2) : ((m == 0) ? 1 : 0);
      int k = 40 * (1 + which) + p;
      sext[m][p][k] = __float2bfloat16(
          bf2f(sext[m][p][k]) * 0.9f * dinv[m * 40 + p] * dinv[pmx * 40 + p]);
    }
  }
  __syncthreads();

  // ---- phase C: h0 = relu(x @ W0 + b0), k-outer blocked ----
  uint2 h0r[9][2];
  {
    f32x4 acc[9][2];
    #pragma unroll
    for (int s = 0; s < 9; s++)
      #pragma unroll
      for (int c = 0; c < 2; c++) acc[s][c] = (f32x4){0.f,0.f,0.f,0.f};
    #pragma unroll
    for (int k0 = 0; k0 < NDIM; k0 += 32) {
      short8 bfw[2];
      #pragma unroll
      for (int c = 0; c < 2; c++)
        bfw[c] = *(const short8*)&Wt[cols[c] * NDIM + k0 + lk];
      short8 af[9];
      #pragma unroll
      for (int s = 0; s < 9; s++)
        af[s] = *(const short8*)&xls[s / 3][arows[s % 3]][k0 + lk];
      #pragma unroll
      for (int s = 0; s < 9; s++)
        #pragma unroll
        for (int c = 0; c < 2; c++)
          acc[s][c] = __builtin_amdgcn_mfma_f32_16x16x32_bf16(af[s], bfw[c], acc[s][c], 0, 0, 0);
    }
    #pragma unroll
    for (int s = 0; s < 9; s++) {
      int p0 = (s % 3) * 16 + (ln >> 4) * 4;
      #pragma unroll
      for (int c = 0; c < 2; c++) {
        float bias = b0[cols[c]];
        bfpk4 pk;
        #pragma unroll
        for (int rr = 0; rr < 4; rr++)
          pk.h[rr] = __float2bfloat16(fmaxf(acc[s][c][rr] + bias, 0.f));
        h0r[s][c] = pk.u;
        if (p0 < L_DIA) *(uint2*)&hls[s / 3][cols[c]][p0] = pk.u;
      }
    }
  }
  __syncthreads();

  // ---- 4 GCN layers ----
  const float thetas[NLAYERS] = {0.40546510810816438f, 0.22314355131420976f,
                                 0.15415067982725836f, 0.11778303565638346f};
  #pragma unroll
  for (int li = 0; li < NLAYERS; li++) {
    float th = thetas[li], onemt = 1.f - th;
    const __hip_bfloat16* Wl = Wt + (li + 1) * NDIM * NDIM;

    // stage 1: sup = S_ext @ [h;h_pm0;h_pm1] + 0.1*h0 -> xls (bf16)
    {
      f32x4 acc[9][2];
      #pragma unroll
      for (int s = 0; s < 9; s++)
        #pragma unroll
        for (int c = 0; c < 2; c++) acc[s][c] = (f32x4){0.f,0.f,0.f,0.f};
      #pragma unroll
      for (int j = 0; j < 4; j++) {
        short8 bfv[3][2];
        #pragma unroll
        for (int mm = 0; mm < 3; mm++) {
          int pm0 = (mm == 0) ? 1 : 0, pm1 = (mm == 2) ? 1 : 2;
          int kk = j * 32 + lk;
          int srcm, brow;
          if (kk < 40)       { srcm = mm;  brow = kk; }
          else if (kk < 80)  { srcm = pm0; brow = kk - 40; }
          else if (kk < 120) { srcm = pm1; brow = kk - 80; }
          else               { srcm = pm1; brow = 32; }   // af is zero here
          #pragma unroll
          for (int c = 0; c < 2; c++)
            bfv[mm][c] = *(const short8*)&hls[srcm][cols[c]][brow];
        }
        short8 af[9];
        #pragma unroll
        for (int s = 0; s < 9; s++)
          af[s] = *(const short8*)&sext[s / 3][arows[s % 3]][j * 32 + lk];
        #pragma unroll
        for (int s = 0; s < 9; s++)
          #pragma unroll
          for (int c = 0; c < 2; c++)
            acc[s][c] = __builtin_amdgcn_mfma_f32_16x16x32_bf16(af[s], bfv[s / 3][c], acc[s][c], 0, 0, 0);
      }
      #pragma unroll
      for (int s = 0; s < 9; s++) {
        int p0 = (s % 3) * 16 + (ln >> 4) * 4;
        #pragma unroll
        for (int c = 0; c < 2; c++) {
          bfpk4 h0p; h0p.u = h0r[s][c];
          if (p0 < L_DIA) {
            #pragma unroll
            for (int rr = 0; rr < 4; rr++)
              xls[s / 3][p0 + rr][cols[c]] =
                  __float2bfloat16(acc[s][c][rr] + 0.1f * bf2f(h0p.h[rr]));
          }
        }
      }
    }
    __syncthreads();

    // stage 2: h_new = relu(theta*(sup@W) + (1-theta)*sup)
    {
      f32x4 o[9][2];
      #pragma unroll
      for (int s = 0; s < 9; s++)
        #pragma unroll
        for (int c = 0; c < 2; c++) o[s][c] = (f32x4){0.f,0.f,0.f,0.f};
      #pragma unroll
      for (int k0 = 0; k0 < NDIM; k0 += 32) {
        short8 bfw[2];
        #pragma unroll
        for (int c = 0; c < 2; c++)
          bfw[c] = *(const short8*)&Wl[cols[c] * NDIM + k0 + lk];
        short8 af[9];
        #pragma unroll
        for (int s = 0; s < 9; s++)
          af[s] = *(const short8*)&xls[s / 3][arows[s % 3]][k0 + lk];
        #pragma unroll
        for (int s = 0; s < 9; s++)
          #pragma unroll
          for (int c = 0; c < 2; c++)
            o[s][c] = __builtin_amdgcn_mfma_f32_16x16x32_bf16(af[s], bfw[c], o[s][c], 0, 0, 0);
      }
      #pragma unroll
      for (int s = 0; s < 9; s++) {
        int m = s / 3;
        int p0 = (s % 3) * 16 + (ln >> 4) * 4;
        if (p0 >= L_DIA) continue;
        #pragma unroll
        for (int c = 0; c < 2; c++) {
          int col = cols[c];
          if (li < NLAYERS - 1) {
            bfpk4 pk;
            #pragma unroll
            for (int rr = 0; rr < 4; rr++) {
              float supv = bf2f(xls[m][p0 + rr][col]);
              pk.h[rr] = __float2bfloat16(fmaxf(th * o[s][c][rr] + onemt * supv, 0.f));
            }
            *(uint2*)&hls[m][col][p0] = pk.u;
          } else {
            #pragma unroll
            for (int rr = 0; rr < 4; rr++) {
              float supv = bf2f(xls[m][p0 + rr][col]);
              out[(b * L_DIA + p0 + rr) * 1536 + m * 512 + 256 + col] =
                  fmaxf(th * o[s][c][rr] + onemt * supv, 0.f);
            }
          }
        }
      }
    }
    __syncthreads();
  }
}

// ---------------------------------------------------------------------------
extern "C" void kernel_launch(void* const* d_in, const int* in_sizes, int n_in,
                              void* d_out, int out_size, void* d_ws, size_t ws_size,
                              hipStream_t stream) {
  const float* a     = (const float*)d_in[0];
  const float* v     = (const float*)d_in[1];
  const float* lf    = (const float*)d_in[2];
  const float* qmask = (const float*)d_in[3];
  const float* spk   = (const float*)d_in[4];
  const float* W0    = (const float*)d_in[5];
  const float* b0    = (const float*)d_in[6];
  const float* Wc    = (const float*)d_in[7];
  float* out = (float*)d_out;

  __hip_bfloat16* Wt = (__hip_bfloat16*)d_ws;   // 5*256*256 bf16 = 640 KB

  k_wt<<<dim3(4, 4, 5), 256, 0, stream>>>(W0, Wc, Wt);
  k_main<<<B_DIA, 512, 0, stream>>>(a, v, lf, qmask, spk, b0, Wt, out);
}